// Round 16
// baseline (144.799 us; speedup 1.0000x reference)
//
#include <hip/hip_runtime.h>

#define B 64
#define N 1024
#define E 16384
#define WPR 32          // words per adjacency row = N/32
#define NITER 5
#define CSR_SLOTS (E + N)   // even-aligned per-node alloc: <=1 pad slot/node
#define MAGIC 0xC0FFEE11u

// ---- workspace layout (bytes) ---- (NO memset: every region fully stored
// before any read; done[] uses a MAGIC sentinel, 0xAA poison != MAGIC)
#define ADJ_OFF   0
#define ADJ_BYTES ((size_t)B * N * WPR * 4)
#define FEATS_OFF ADJ_BYTES
#define DIAG_OFF  (FEATS_OFF + (size_t)B * N * 4)
#define DONE_OFF  (DIAG_OFF + 256)

// Bit adjacency built in LDS, full rows STORED to global. R14 proved the
// bitmask is load-bearing (parallel atomicOr dedup vs 85us in-block CSR).
__global__ void __launch_bounds__(1024) build_adj_k(const int* __restrict__ src,
                                                    const int* __restrict__ dst,
                                                    unsigned int* __restrict__ adj) {
    __shared__ unsigned int s_adj[512 * WPR];       // 64 KiB: 512 rows
    int t = threadIdx.x;
    int b = blockIdx.x >> 1;
    int half = blockIdx.x & 1;
    int row_base = half << 9;

    uint4* s4 = (uint4*)s_adj;
#pragma unroll
    for (int k = 0; k < 4; ++k) s4[t + k * 1024] = make_uint4(0, 0, 0, 0);
    __syncthreads();

    const int* sg = src + (size_t)b * E;
    const int* dg = dst + (size_t)b * E;
#pragma unroll
    for (int k = 0; k < 16; ++k) {
        int e = t + k * 1024;
        int s = sg[e];
        int d = dg[e];
        int r = s - row_base;
        if ((unsigned)r < 512u)
            atomicOr(&s_adj[r * WPR + (d >> 5)], 1u << (d & 31));  // idempotent dedup
    }
    __syncthreads();

    uint4* g4 = (uint4*)(adj + ((size_t)b * N + row_base) * WPR);
#pragma unroll
    for (int k = 0; k < 4; ++k) g4[t + k * 1024] = s4[t + k * 1024];
}

// One block per graph: R12's proven Phase A/B verbatim; Phase C fuses the
// Gram row via MAGIC handshake. R16: poll with device-scope atomic LOADS
// (not RMWs) — R15's atomicAdd(p,0) poll made 4096 same-line RMWs/round,
// a ~40us serialization convoy that also delayed the release exchanges.
__global__ void __launch_bounds__(1024) wl_mega_k(const unsigned int* __restrict__ adj,
                                                  const int* __restrict__ lab0,
                                                  const float* __restrict__ hw,
                                                  unsigned int* __restrict__ feats,
                                                  float* __restrict__ diag,
                                                  unsigned int* __restrict__ done,
                                                  float* __restrict__ gout) {
    __shared__ unsigned short s_nbr[CSR_SLOTS];     // 34 KB even-aligned CSR
    __shared__ int s_lab[N + 2];                    // +sentinel slot (=0)
    __shared__ int s_hist[N];
    __shared__ int s_scan[N];
    __shared__ float s_grp[N];
    __shared__ int s_flag[N];
    __shared__ unsigned int s_feats[N];
    __shared__ int s_wsum[16];
    __shared__ float s_mn[17], s_mx[17];
    __shared__ int s_K;
    __shared__ int s_anytie;
    int b = blockIdx.x, t = threadIdx.x;
    int lane = t & 63, w = t >> 6;

    // ---- Phase A: row -> deg/CSR/K, init labels + bincount ----
    uint4 r[8];
    const uint4* rowg = (const uint4*)(adj + ((size_t)b * N + t) * WPR);
#pragma unroll
    for (int k = 0; k < 8; ++k) r[k] = rowg[k];
    int dg = 0;
#pragma unroll
    for (int k = 0; k < 8; ++k)
        dg += __popc(r[k].x) + __popc(r[k].y) + __popc(r[k].z) + __popc(r[k].w);
    int alloc = (dg + 1) & ~1;                      // even per-node CSR alloc

    int f = alloc;                                  // wave scan of alloc
#pragma unroll
    for (int d2 = 1; d2 < 64; d2 <<= 1) {
        int v = __shfl_up(f, d2);
        if (lane >= d2) f += v;
    }
    int km = dg;
#pragma unroll
    for (int o = 32; o > 0; o >>= 1) km = max(km, __shfl_down(km, o));
    if (lane == 63) s_wsum[w] = f;
    if (lane == 0)  s_scan[w] = km;                 // scratch for K partials

    int l0 = lab0[(size_t)b * N + t];
    s_lab[t] = l0;
    s_feats[t] = 0;
    s_hist[t] = 0;
    s_flag[t] = 0;
    if (t == 0) { s_lab[N] = 0; s_anytie = 0; }
    __syncthreads();                                        // A1
    if (t == 0) {                                   // serial combine (R7-style)
        int run = 0, m = 0;
#pragma unroll
        for (int k = 0; k < 16; ++k) {
            int tmp = s_wsum[k]; s_wsum[k] = run; run += tmp;
            m = max(m, s_scan[k]);
        }
        s_K = m;
    }
    // init label bincount (labels < 16) via ballot
#pragma unroll
    for (int v = 0; v < 16; ++v) {
        unsigned long long m = __ballot(l0 == v);
        if (lane == v) {
            int c = __popcll(m);
            if (c) atomicAdd(&s_feats[v], (unsigned)c);
        }
    }
    __syncthreads();                                        // A2
    int start = (f - alloc) + s_wsum[w];            // even => u32-aligned

    // pack own row's set bits ONCE -> u16 list; pad odd deg with sentinel N
    {
        int idx = start;
#pragma unroll
        for (int k = 0; k < 8; ++k) {
            unsigned int wv[4] = { r[k].x, r[k].y, r[k].z, r[k].w };
#pragma unroll
            for (int c2 = 0; c2 < 4; ++c2) {
                unsigned int word = wv[c2];
                int bb = (k * 4 + c2) << 5;
                while (word) {
                    int j = __ffs(word) - 1;
                    word &= word - 1;
                    s_nbr[idx++] = (unsigned short)(bb + j);
                }
            }
        }
        if (dg & 1) s_nbr[idx] = (unsigned short)N; // sentinel -> adds 0
    }
    float Kf = (float)s_K;
    float w0 = hw[0], w1 = hw[1];
    int pairs = alloc >> 1;
    int pstart = start >> 1;
    __syncthreads();                                        // A3

    // ---- Phase B: 5 WL iterations (R12-proven, verbatim) ----
    for (int it = 0; it < NITER; ++it) {
        int s = 0;
        const unsigned int* nbr32 = (const unsigned int*)s_nbr;
        for (int k = 0; k < pairs; ++k) {
            unsigned int pr = nbr32[pstart + k];
            s += s_lab[pr & 0xFFFFu] + s_lab[pr >> 16];
        }
        float t1 = __fmul_rn(__fmul_rn(Kf, w0), (float)s_lab[t]);
        float t2 = __fmul_rn(w1, __fsub_rn(__fadd_rn((float)s, (float)dg), Kf));
        float h  = __fadd_rn(t1, t2);

        float mn = h, mx = h;
#pragma unroll
        for (int o = 32; o > 0; o >>= 1) {
            mn = fminf(mn, __shfl_down(mn, o));
            mx = fmaxf(mx, __shfl_down(mx, o));
        }
        if (lane == 0) { s_mn[w] = mn; s_mx[w] = mx; }
        __syncthreads();                                    // B1
        if (t == 0) {
            float a = s_mn[0], c = s_mx[0];
#pragma unroll
            for (int k = 1; k < 16; ++k) { a = fminf(a, s_mn[k]); c = fmaxf(c, s_mx[k]); }
            s_mn[16] = a; s_mx[16] = c;
        }
        __syncthreads();                                    // B2
        float fmn = s_mn[16];
        float span = s_mx[16] - fmn;
        float scale = (span > 0.f) ? (1023.0f / span) : 0.f;
        int bucket = min((int)((h - fmn) * scale), 1023);   // order-preserving
        int off_in = atomicAdd(&s_hist[bucket], 1);
        __syncthreads();                                    // B3

        f = s_hist[t];
#pragma unroll
        for (int d2 = 1; d2 < 64; d2 <<= 1) {
            int v = __shfl_up(f, d2);
            if (lane >= d2) f += v;
        }
        if (lane == 63) s_wsum[w] = f;
        __syncthreads();                                    // B4
        if (t == 0) {
            int run = 0;
#pragma unroll
            for (int k = 0; k < 16; ++k) { int tmp = s_wsum[k]; s_wsum[k] = run; run += tmp; }
        }
        __syncthreads();                                    // B5
        s_scan[t] = f + s_wsum[w];
        __syncthreads();                                    // B6

        int bs = s_scan[bucket] - s_hist[bucket];
        int be = s_scan[bucket];
        s_grp[bs + off_in] = h;
        __syncthreads();                                    // B7

        int c = bs;                 // lower buckets strictly less (monotone map)
        int eq = 0;
        for (int k = bs; k < be; ++k) {
            float g = s_grp[k];
            c += (g < h);
            eq += (g == h);
        }
        if (eq > 1) s_anytie = it + 1;  // sentinel: stale iters self-invalidate
        s_hist[t] = 0;                  // re-zero for next iter
        __syncthreads();                                    // B8

        int rank;
        if (s_anytie != it + 1) {
            rank = c;                   // distinct keys: c IS the dense rank
            s_lab[t] = rank;
            s_feats[rank] += 1u;        // permutation -> conflict-free
        } else {
            s_flag[c] = 1;              // class start (same class -> same c)
            __syncthreads();                                // T1
            int f2 = s_flag[t];
#pragma unroll
            for (int d2 = 1; d2 < 64; d2 <<= 1) {
                int v = __shfl_up(f2, d2);
                if (lane >= d2) f2 += v;
            }
            if (lane == 63) s_wsum[w] = f2;
            __syncthreads();                                // T2
            if (t == 0) {
                int run = 0;
#pragma unroll
                for (int k = 0; k < 16; ++k) { int tmp = s_wsum[k]; s_wsum[k] = run; run += tmp; }
            }
            __syncthreads();                                // T3
            s_scan[t] = f2 + s_wsum[w];
            s_flag[t] = 0;              // own flag consumed above
            __syncthreads();                                // T4
            rank = s_scan[c] - 1;
            s_lab[t] = rank;
            atomicAdd(&s_feats[rank], 1u);
        }
        __syncthreads();                                    // B9
    }

    // ---- Phase C: publish + handshake + own Gram row ----
    unsigned int fv = s_feats[t];
    feats[(size_t)b * N + t] = fv;
    int sq = (int)(fv * fv);
#pragma unroll
    for (int o = 32; o > 0; o >>= 1) sq += __shfl_down(sq, o);
    if (lane == 0) s_wsum[w] = sq;
    __syncthreads();
    if (t == 0) {
        int tot = 0;
#pragma unroll
        for (int k = 0; k < 16; ++k) tot += s_wsum[k];
        diag[b] = (float)tot;           // int-exact
    }
    __threadfence();                    // release: drain feats+diag
    if (t == 0) atomicExch(&done[b], MAGIC);   // 64 RMWs total — no convoy
    if (w == 0) {                       // wave0 lane i polls done[i] with
        unsigned int v;                 // device-scope atomic LOADS (no RMW)
        do {
            v = __hip_atomic_load(&done[lane], __ATOMIC_RELAXED,
                                  __HIP_MEMORY_SCOPE_AGENT);
            if (__ballot(v != MAGIC) == 0ull) break;
            __builtin_amdgcn_s_sleep(2);        // backoff: cut L2 pressure
        } while (true);
    }
    __syncthreads();
    __threadfence();                    // acquire side

    float db = diag[b];
#pragma unroll
    for (int jj = 0; jj < 4; ++jj) {
        int j = w * 4 + jj;             // 16 waves x 4 = all 64 columns
        const uint4* fj = (const uint4*)(feats + (size_t)j * N);
        const uint4* fi = (const uint4*)s_feats;
        int s = 0;
#pragma unroll
        for (int k = 0; k < 4; ++k) {
            uint4 vb = fj[lane + k * 64];
            uint4 va = fi[lane + k * 64];
            s += (int)(va.x * vb.x) + (int)(va.y * vb.y)
               + (int)(va.z * vb.z) + (int)(va.w * vb.w);
        }
#pragma unroll
        for (int o = 32; o > 0; o >>= 1) s += __shfl_down(s, o);
        if (lane == 0) gout[b * B + j] = (float)s / sqrtf(db * diag[j]);
    }
}

extern "C" void kernel_launch(void* const* d_in, const int* in_sizes, int n_in,
                              void* d_out, int out_size, void* d_ws, size_t ws_size,
                              hipStream_t stream) {
    const int*   esrc = (const int*)d_in[0];
    const int*   edst = (const int*)d_in[1];
    const int*   lab0 = (const int*)d_in[2];
    const float* hw   = (const float*)d_in[3];

    char* ws = (char*)d_ws;
    unsigned int* adj   = (unsigned int*)(ws + ADJ_OFF);
    unsigned int* feats = (unsigned int*)(ws + FEATS_OFF);
    float*        diag  = (float*)(ws + DIAG_OFF);
    unsigned int* done  = (unsigned int*)(ws + DONE_OFF);

    build_adj_k<<<B * 2, 1024, 0, stream>>>(esrc, edst, adj);
    wl_mega_k<<<B, 1024, 0, stream>>>(adj, lab0, hw, feats, diag, done,
                                      (float*)d_out);
}

// Round 17
// 114.778 us; speedup vs baseline: 1.2616x; 1.2616x over previous
//
#include <hip/hip_runtime.h>

#define B 64
#define N 1024
#define E 16384
#define WPR 32          // words per adjacency row = N/32
#define NITER 5
#define CSR_SLOTS (E + N)   // even-aligned per-node alloc: <=1 pad slot/node
#define CH_ROWS 128
#define CH_WORDS (CH_ROWS * WPR)    // 4096 u32 = 16 KB chunk

// ---- workspace layout (bytes) ---- (NO memset: feats/diag fully stored
// before any read; harness 0xAA poison harmless)
#define FEATS_OFF 0
#define DIAG_OFF  ((size_t)B * N * 4)

// ONE WL kernel per graph-block. R17: the bitmask adjacency never touches
// global memory — built in LDS 128 rows at a time (8 chunks x 16KB) from
// register-held edges, with the PROVEN parallel atomicOr dedup (R14 showed
// serial CSR dedup is a disaster; R5-R12 showed bitmask dedup is free).
// Each thread captures its own row into r[8] regs when its chunk is live;
// Phase A then continues exactly as R12 (popcount/scan/pack). Gram stays a
// separate kernel: R15/R16 proved in-kernel global handshakes cost ~20us
// regardless of poll mechanism (per-block L2 release/acquire maintenance).
__global__ void __launch_bounds__(1024) wl_mega_k(const int* __restrict__ src,
                                                  const int* __restrict__ dstp,
                                                  const int* __restrict__ lab0,
                                                  const float* __restrict__ hw,
                                                  unsigned int* __restrict__ feats,
                                                  float* __restrict__ diag) {
    __shared__ union {
        unsigned int chunk[CH_WORDS];               // Phase A: 16KB bitmask tile
        struct {                                    // Phase B: rank arrays 16KB
            int hist[N];
            int scan[N];
            float grp[N];
            int flag[N];
        } pb;
    } u;
    __shared__ unsigned short s_nbr[CSR_SLOTS];     // 34 KB even-aligned CSR
    __shared__ int s_lab[N + 2];                    // +sentinel slot (=0)
    __shared__ unsigned int s_feats[N];
    __shared__ int s_wsum[16];
    __shared__ int s_kp[16];
    __shared__ float s_mn[17], s_mx[17];
    __shared__ int s_K;
    __shared__ int s_anytie;
    int b = blockIdx.x, t = threadIdx.x;
    int lane = t & 63, w = t >> 6;

    // ---- Phase A0: edges + labels to registers/LDS ----
    const int* sg = src + (size_t)b * E;
    const int* dg_ = dstp + (size_t)b * E;
    int es[16], ed[16];
#pragma unroll
    for (int k = 0; k < 16; ++k) {                  // coalesced, 1 block/graph
        es[k] = sg[t + k * 1024];
        ed[k] = dg_[t + k * 1024];
    }
    int l0 = lab0[(size_t)b * N + t];
    s_lab[t] = l0;
    s_feats[t] = 0;
    if (t == 0) { s_lab[N] = 0; s_anytie = 0; }
    __syncthreads();                                        // P0
    // init label bincount (labels < 16) via ballot
#pragma unroll
    for (int v = 0; v < 16; ++v) {
        unsigned long long m = __ballot(l0 == v);
        if (lane == v) {
            int c = __popcll(m);
            if (c) atomicAdd(&s_feats[v], (unsigned)c);
        }
    }

    // ---- Phase A1: chunked LDS bitmask build; own row -> r[8] regs ----
    uint4 r[8];
#pragma unroll 1
    for (int c = 0; c < 8; ++c) {
        ((uint4*)u.chunk)[t] = make_uint4(0, 0, 0, 0);      // 16KB zero
        __syncthreads();                                    // C1
#pragma unroll
        for (int k = 0; k < 16; ++k) {
            int rr = es[k] - (c << 7);
            if ((unsigned)rr < (unsigned)CH_ROWS)
                atomicOr(&u.chunk[rr * WPR + (ed[k] >> 5)], 1u << (ed[k] & 31));
        }
        __syncthreads();                                    // C2
        int rl = t - (c << 7);
        if ((unsigned)rl < (unsigned)CH_ROWS) {             // own row lives here
            const uint4* row = (const uint4*)(u.chunk + rl * WPR);
#pragma unroll
            for (int k = 0; k < 8; ++k) r[k] = row[k];
        }
        __syncthreads();                                    // C3
    }

    // ---- Phase A2: deg/alloc/K/CSR starts + pack (R12-proven) ----
    int dg = 0;
#pragma unroll
    for (int k = 0; k < 8; ++k)
        dg += __popc(r[k].x) + __popc(r[k].y) + __popc(r[k].z) + __popc(r[k].w);
    int alloc = (dg + 1) & ~1;                      // even per-node CSR alloc

    int f = alloc;                                  // wave scan of alloc
#pragma unroll
    for (int d2 = 1; d2 < 64; d2 <<= 1) {
        int v = __shfl_up(f, d2);
        if (lane >= d2) f += v;
    }
    int km = dg;
#pragma unroll
    for (int o = 32; o > 0; o >>= 1) km = max(km, __shfl_down(km, o));
    if (lane == 63) s_wsum[w] = f;
    if (lane == 0)  s_kp[w] = km;
    __syncthreads();                                        // A1
    if (t == 0) {                                   // serial combine (R7-style)
        int run = 0, m = 0;
#pragma unroll
        for (int k = 0; k < 16; ++k) {
            int tmp = s_wsum[k]; s_wsum[k] = run; run += tmp;
            m = max(m, s_kp[k]);
        }
        s_K = m;
    }
    __syncthreads();                                        // A2
    int start = (f - alloc) + s_wsum[w];            // even => u32-aligned
    u.pb.hist[t] = 0;                               // union now Phase B's
    u.pb.flag[t] = 0;

    // pack own row's set bits ONCE -> u16 list; pad odd deg with sentinel N
    {
        int idx = start;
#pragma unroll
        for (int k = 0; k < 8; ++k) {
            unsigned int wv[4] = { r[k].x, r[k].y, r[k].z, r[k].w };
#pragma unroll
            for (int c2 = 0; c2 < 4; ++c2) {
                unsigned int word = wv[c2];
                int bb = (k * 4 + c2) << 5;
                while (word) {
                    int j = __ffs(word) - 1;
                    word &= word - 1;
                    s_nbr[idx++] = (unsigned short)(bb + j);
                }
            }
        }
        if (dg & 1) s_nbr[idx] = (unsigned short)N; // sentinel -> adds 0
    }
    float Kf = (float)s_K;
    float w0 = hw[0], w1 = hw[1];
    int pairs = alloc >> 1;
    int pstart = start >> 1;
    __syncthreads();                                        // A3

    // ---- Phase B: 5 WL iterations (R12-proven, verbatim) ----
    for (int it = 0; it < NITER; ++it) {
        int s = 0;
        const unsigned int* nbr32 = (const unsigned int*)s_nbr;
        for (int k = 0; k < pairs; ++k) {
            unsigned int pr = nbr32[pstart + k];
            s += s_lab[pr & 0xFFFFu] + s_lab[pr >> 16];
        }
        float t1 = __fmul_rn(__fmul_rn(Kf, w0), (float)s_lab[t]);
        float t2 = __fmul_rn(w1, __fsub_rn(__fadd_rn((float)s, (float)dg), Kf));
        float h  = __fadd_rn(t1, t2);

        float mn = h, mx = h;
#pragma unroll
        for (int o = 32; o > 0; o >>= 1) {
            mn = fminf(mn, __shfl_down(mn, o));
            mx = fmaxf(mx, __shfl_down(mx, o));
        }
        if (lane == 0) { s_mn[w] = mn; s_mx[w] = mx; }
        __syncthreads();                                    // B1
        if (t == 0) {
            float a = s_mn[0], c = s_mx[0];
#pragma unroll
            for (int k = 1; k < 16; ++k) { a = fminf(a, s_mn[k]); c = fmaxf(c, s_mx[k]); }
            s_mn[16] = a; s_mx[16] = c;
        }
        __syncthreads();                                    // B2
        float fmn = s_mn[16];
        float span = s_mx[16] - fmn;
        float scale = (span > 0.f) ? (1023.0f / span) : 0.f;
        int bucket = min((int)((h - fmn) * scale), 1023);   // order-preserving
        int off_in = atomicAdd(&u.pb.hist[bucket], 1);
        __syncthreads();                                    // B3

        f = u.pb.hist[t];
#pragma unroll
        for (int d2 = 1; d2 < 64; d2 <<= 1) {
            int v = __shfl_up(f, d2);
            if (lane >= d2) f += v;
        }
        if (lane == 63) s_wsum[w] = f;
        __syncthreads();                                    // B4
        if (t == 0) {
            int run = 0;
#pragma unroll
            for (int k = 0; k < 16; ++k) { int tmp = s_wsum[k]; s_wsum[k] = run; run += tmp; }
        }
        __syncthreads();                                    // B5
        u.pb.scan[t] = f + s_wsum[w];
        __syncthreads();                                    // B6

        int bs = u.pb.scan[bucket] - u.pb.hist[bucket];
        int be = u.pb.scan[bucket];
        u.pb.grp[bs + off_in] = h;
        __syncthreads();                                    // B7

        int c = bs;                 // lower buckets strictly less (monotone map)
        int eq = 0;
        for (int k = bs; k < be; ++k) {
            float g = u.pb.grp[k];
            c += (g < h);
            eq += (g == h);
        }
        if (eq > 1) s_anytie = it + 1;  // sentinel: stale iters self-invalidate
        u.pb.hist[t] = 0;               // re-zero for next iter
        __syncthreads();                                    // B8

        int rank;
        if (s_anytie != it + 1) {
            rank = c;                   // distinct keys: c IS the dense rank
            s_lab[t] = rank;
            s_feats[rank] += 1u;        // permutation -> conflict-free
        } else {
            u.pb.flag[c] = 1;           // class start (same class -> same c)
            __syncthreads();                                // T1
            int f2 = u.pb.flag[t];
#pragma unroll
            for (int d2 = 1; d2 < 64; d2 <<= 1) {
                int v = __shfl_up(f2, d2);
                if (lane >= d2) f2 += v;
            }
            if (lane == 63) s_wsum[w] = f2;
            __syncthreads();                                // T2
            if (t == 0) {
                int run = 0;
#pragma unroll
                for (int k = 0; k < 16; ++k) { int tmp = s_wsum[k]; s_wsum[k] = run; run += tmp; }
            }
            __syncthreads();                                // T3
            u.pb.scan[t] = f2 + s_wsum[w];
            u.pb.flag[t] = 0;           // own flag consumed above
            __syncthreads();                                // T4
            rank = u.pb.scan[c] - 1;
            s_lab[t] = rank;
            atomicAdd(&s_feats[rank], 1u);
        }
        __syncthreads();                                    // B9
    }

    // ---- Phase C: feats out + fused diag[b] (int exact) ----
    unsigned int fv = s_feats[t];
    feats[(size_t)b * N + t] = fv;
    int sq = (int)(fv * fv);
#pragma unroll
    for (int o = 32; o > 0; o >>= 1) sq += __shfl_down(sq, o);
    if (lane == 0) s_wsum[w] = sq;
    __syncthreads();
    if (t == 0) {
        int tot = 0;
#pragma unroll
        for (int k = 0; k < 16; ++k) tot += s_wsum[k];
        diag[b] = (float)tot;
    }
}

// gram+normalize fused (R12-measured ~4us): one block per row i; f_i staged
// in LDS; int dots exact; writes normalized value straight to d_out.
__global__ void __launch_bounds__(256) gram_k(const unsigned int* __restrict__ feats,
                                              const float* __restrict__ diag,
                                              float* __restrict__ out) {
    __shared__ unsigned int s_fi[N];
    int i = blockIdx.x, t = threadIdx.x;
    int lane = t & 63, w = t >> 6;
    ((uint4*)s_fi)[t] = ((const uint4*)(feats + (size_t)i * N))[t];
    __syncthreads();
    float di = diag[i];
    for (int jj = 0; jj < 16; ++jj) {
        int j = w * 16 + jj;
        const uint4* fj = (const uint4*)(feats + (size_t)j * N);
        const uint4* fi = (const uint4*)s_fi;
        int s = 0;
#pragma unroll
        for (int k = 0; k < 4; ++k) {
            uint4 vb = fj[lane + k * 64];
            uint4 va = fi[lane + k * 64];
            s += (int)(va.x * vb.x) + (int)(va.y * vb.y)
               + (int)(va.z * vb.z) + (int)(va.w * vb.w);
        }
#pragma unroll
        for (int off = 32; off > 0; off >>= 1) s += __shfl_down(s, off);
        if (lane == 0) out[i * B + j] = (float)s / sqrtf(di * diag[j]);
    }
}

extern "C" void kernel_launch(void* const* d_in, const int* in_sizes, int n_in,
                              void* d_out, int out_size, void* d_ws, size_t ws_size,
                              hipStream_t stream) {
    const int*   esrc = (const int*)d_in[0];
    const int*   edst = (const int*)d_in[1];
    const int*   lab0 = (const int*)d_in[2];
    const float* hw   = (const float*)d_in[3];

    char* ws = (char*)d_ws;
    unsigned int* feats = (unsigned int*)(ws + FEATS_OFF);
    float*        diag  = (float*)(ws + DIAG_OFF);

    wl_mega_k<<<B, 1024, 0, stream>>>(esrc, edst, lab0, hw, feats, diag);
    gram_k<<<B, 256, 0, stream>>>(feats, diag, (float*)d_out);
}

// Round 18
// 114.240 us; speedup vs baseline: 1.2675x; 1.0047x over previous
//
#include <hip/hip_runtime.h>

#define B 64
#define N 1024
#define E 16384
#define WPR 32          // words per adjacency row = N/32
#define NITER 5
#define CSR_SLOTS (E + N)   // even-aligned per-node alloc: <=1 pad slot/node
#define CH_ROWS 128
#define CH_WORDS (CH_ROWS * WPR)    // 4096 u32 = 16 KB chunk

// ---- workspace layout (bytes) ---- (NO memset: feats/diag fully stored
// before any read; harness 0xAA poison harmless)
#define FEATS_OFF 0
#define DIAG_OFF  ((size_t)B * N * 4)

// ONE WL kernel per graph-block (R17 structure, measured 114.8us total).
// R18: XOR-swizzled chunk layout — logical uint4-group g of row rr lives at
// physical slot (g+rr)&7. R17's capture read rows at stride 128B (bank-
// aligned -> 16-way conflicts, +700K conflict cycles); swizzled capture is
// conflict-free (consecutive lanes hit all 32 banks). Scatter/zero unchanged.
__global__ void __launch_bounds__(1024) wl_mega_k(const int* __restrict__ src,
                                                  const int* __restrict__ dstp,
                                                  const int* __restrict__ lab0,
                                                  const float* __restrict__ hw,
                                                  unsigned int* __restrict__ feats,
                                                  float* __restrict__ diag) {
    __shared__ union {
        unsigned int chunk[CH_WORDS];               // Phase A: 16KB bitmask tile
        struct {                                    // Phase B: rank arrays 16KB
            int hist[N];
            int scan[N];
            float grp[N];
            int flag[N];
        } pb;
    } u;
    __shared__ unsigned short s_nbr[CSR_SLOTS];     // 34 KB even-aligned CSR
    __shared__ int s_lab[N + 2];                    // +sentinel slot (=0)
    __shared__ unsigned int s_feats[N];
    __shared__ int s_wsum[16];
    __shared__ int s_kp[16];
    __shared__ float s_mn[17], s_mx[17];
    __shared__ int s_K;
    __shared__ int s_anytie;
    int b = blockIdx.x, t = threadIdx.x;
    int lane = t & 63, w = t >> 6;

    // ---- Phase A0: edges + labels to registers/LDS ----
    const int* sg = src + (size_t)b * E;
    const int* dg_ = dstp + (size_t)b * E;
    int es[16], ed[16];
#pragma unroll
    for (int k = 0; k < 16; ++k) {                  // coalesced, 1 block/graph
        es[k] = sg[t + k * 1024];
        ed[k] = dg_[t + k * 1024];
    }
    int l0 = lab0[(size_t)b * N + t];
    s_lab[t] = l0;
    s_feats[t] = 0;
    if (t == 0) { s_lab[N] = 0; s_anytie = 0; }
    __syncthreads();                                        // P0
    // init label bincount (labels < 16) via ballot
#pragma unroll
    for (int v = 0; v < 16; ++v) {
        unsigned long long m = __ballot(l0 == v);
        if (lane == v) {
            int c = __popcll(m);
            if (c) atomicAdd(&s_feats[v], (unsigned)c);
        }
    }

    // ---- Phase A1: chunked LDS bitmask build (swizzled), row -> r[8] ----
    uint4 r[8];
#pragma unroll 1
    for (int c = 0; c < 8; ++c) {
        ((uint4*)u.chunk)[t] = make_uint4(0, 0, 0, 0);      // 16KB zero
        __syncthreads();                                    // C1
#pragma unroll
        for (int k = 0; k < 16; ++k) {
            int rr = es[k] - (c << 7);
            if ((unsigned)rr < (unsigned)CH_ROWS) {
                int wlog = ed[k] >> 5;                      // logical word 0..31
                int g = wlog >> 2;                          // logical group 0..7
                int p = (g + rr) & 7;                       // swizzled slot
                atomicOr(&u.chunk[rr * WPR + p * 4 + (wlog & 3)],
                         1u << (ed[k] & 31));
            }
        }
        __syncthreads();                                    // C2
        int rl = t - (c << 7);
        if ((unsigned)rl < (unsigned)CH_ROWS) {             // own row lives here
            const uint4* row4 = (const uint4*)(u.chunk + rl * WPR);
#pragma unroll
            for (int g = 0; g < 8; ++g)
                r[g] = row4[(g + rl) & 7];                  // conflict-free
        }
        __syncthreads();                                    // C3
    }

    // ---- Phase A2: deg/alloc/K/CSR starts + pack (R12-proven) ----
    int dg = 0;
#pragma unroll
    for (int k = 0; k < 8; ++k)
        dg += __popc(r[k].x) + __popc(r[k].y) + __popc(r[k].z) + __popc(r[k].w);
    int alloc = (dg + 1) & ~1;                      // even per-node CSR alloc

    int f = alloc;                                  // wave scan of alloc
#pragma unroll
    for (int d2 = 1; d2 < 64; d2 <<= 1) {
        int v = __shfl_up(f, d2);
        if (lane >= d2) f += v;
    }
    int km = dg;
#pragma unroll
    for (int o = 32; o > 0; o >>= 1) km = max(km, __shfl_down(km, o));
    if (lane == 63) s_wsum[w] = f;
    if (lane == 0)  s_kp[w] = km;
    __syncthreads();                                        // A1
    if (t == 0) {                                   // serial combine (R7-style)
        int run = 0, m = 0;
#pragma unroll
        for (int k = 0; k < 16; ++k) {
            int tmp = s_wsum[k]; s_wsum[k] = run; run += tmp;
            m = max(m, s_kp[k]);
        }
        s_K = m;
    }
    __syncthreads();                                        // A2
    int start = (f - alloc) + s_wsum[w];            // even => u32-aligned
    u.pb.hist[t] = 0;                               // union now Phase B's
    u.pb.flag[t] = 0;

    // pack own row's set bits ONCE -> u16 list; pad odd deg with sentinel N
    {
        int idx = start;
#pragma unroll
        for (int k = 0; k < 8; ++k) {
            unsigned int wv[4] = { r[k].x, r[k].y, r[k].z, r[k].w };
#pragma unroll
            for (int c2 = 0; c2 < 4; ++c2) {
                unsigned int word = wv[c2];
                int bb = (k * 4 + c2) << 5;
                while (word) {
                    int j = __ffs(word) - 1;
                    word &= word - 1;
                    s_nbr[idx++] = (unsigned short)(bb + j);
                }
            }
        }
        if (dg & 1) s_nbr[idx] = (unsigned short)N; // sentinel -> adds 0
    }
    float Kf = (float)s_K;
    float w0 = hw[0], w1 = hw[1];
    int pairs = alloc >> 1;
    int pstart = start >> 1;
    __syncthreads();                                        // A3

    // ---- Phase B: 5 WL iterations (R12-proven, verbatim) ----
    for (int it = 0; it < NITER; ++it) {
        int s = 0;
        const unsigned int* nbr32 = (const unsigned int*)s_nbr;
        for (int k = 0; k < pairs; ++k) {
            unsigned int pr = nbr32[pstart + k];
            s += s_lab[pr & 0xFFFFu] + s_lab[pr >> 16];
        }
        float t1 = __fmul_rn(__fmul_rn(Kf, w0), (float)s_lab[t]);
        float t2 = __fmul_rn(w1, __fsub_rn(__fadd_rn((float)s, (float)dg), Kf));
        float h  = __fadd_rn(t1, t2);

        float mn = h, mx = h;
#pragma unroll
        for (int o = 32; o > 0; o >>= 1) {
            mn = fminf(mn, __shfl_down(mn, o));
            mx = fmaxf(mx, __shfl_down(mx, o));
        }
        if (lane == 0) { s_mn[w] = mn; s_mx[w] = mx; }
        __syncthreads();                                    // B1
        if (t == 0) {
            float a = s_mn[0], c = s_mx[0];
#pragma unroll
            for (int k = 1; k < 16; ++k) { a = fminf(a, s_mn[k]); c = fmaxf(c, s_mx[k]); }
            s_mn[16] = a; s_mx[16] = c;
        }
        __syncthreads();                                    // B2
        float fmn = s_mn[16];
        float span = s_mx[16] - fmn;
        float scale = (span > 0.f) ? (1023.0f / span) : 0.f;
        int bucket = min((int)((h - fmn) * scale), 1023);   // order-preserving
        int off_in = atomicAdd(&u.pb.hist[bucket], 1);
        __syncthreads();                                    // B3

        f = u.pb.hist[t];
#pragma unroll
        for (int d2 = 1; d2 < 64; d2 <<= 1) {
            int v = __shfl_up(f, d2);
            if (lane >= d2) f += v;
        }
        if (lane == 63) s_wsum[w] = f;
        __syncthreads();                                    // B4
        if (t == 0) {
            int run = 0;
#pragma unroll
            for (int k = 0; k < 16; ++k) { int tmp = s_wsum[k]; s_wsum[k] = run; run += tmp; }
        }
        __syncthreads();                                    // B5
        u.pb.scan[t] = f + s_wsum[w];
        __syncthreads();                                    // B6

        int bs = u.pb.scan[bucket] - u.pb.hist[bucket];
        int be = u.pb.scan[bucket];
        u.pb.grp[bs + off_in] = h;
        __syncthreads();                                    // B7

        int c = bs;                 // lower buckets strictly less (monotone map)
        int eq = 0;
        for (int k = bs; k < be; ++k) {
            float g = u.pb.grp[k];
            c += (g < h);
            eq += (g == h);
        }
        if (eq > 1) s_anytie = it + 1;  // sentinel: stale iters self-invalidate
        u.pb.hist[t] = 0;               // re-zero for next iter
        __syncthreads();                                    // B8

        int rank;
        if (s_anytie != it + 1) {
            rank = c;                   // distinct keys: c IS the dense rank
            s_lab[t] = rank;
            s_feats[rank] += 1u;        // permutation -> conflict-free
        } else {
            u.pb.flag[c] = 1;           // class start (same class -> same c)
            __syncthreads();                                // T1
            int f2 = u.pb.flag[t];
#pragma unroll
            for (int d2 = 1; d2 < 64; d2 <<= 1) {
                int v = __shfl_up(f2, d2);
                if (lane >= d2) f2 += v;
            }
            if (lane == 63) s_wsum[w] = f2;
            __syncthreads();                                // T2
            if (t == 0) {
                int run = 0;
#pragma unroll
                for (int k = 0; k < 16; ++k) { int tmp = s_wsum[k]; s_wsum[k] = run; run += tmp; }
            }
            __syncthreads();                                // T3
            u.pb.scan[t] = f2 + s_wsum[w];
            u.pb.flag[t] = 0;           // own flag consumed above
            __syncthreads();                                // T4
            rank = u.pb.scan[c] - 1;
            s_lab[t] = rank;
            atomicAdd(&s_feats[rank], 1u);
        }
        __syncthreads();                                    // B9
    }

    // ---- Phase C: feats out + fused diag[b] (int exact) ----
    unsigned int fv = s_feats[t];
    feats[(size_t)b * N + t] = fv;
    int sq = (int)(fv * fv);
#pragma unroll
    for (int o = 32; o > 0; o >>= 1) sq += __shfl_down(sq, o);
    if (lane == 0) s_wsum[w] = sq;
    __syncthreads();
    if (t == 0) {
        int tot = 0;
#pragma unroll
        for (int k = 0; k < 16; ++k) tot += s_wsum[k];
        diag[b] = (float)tot;
    }
}

// gram+normalize fused (measured ~4us): one block per row i; f_i staged in
// LDS; int dots exact; writes normalized value straight to d_out.
__global__ void __launch_bounds__(256) gram_k(const unsigned int* __restrict__ feats,
                                              const float* __restrict__ diag,
                                              float* __restrict__ out) {
    __shared__ unsigned int s_fi[N];
    int i = blockIdx.x, t = threadIdx.x;
    int lane = t & 63, w = t >> 6;
    ((uint4*)s_fi)[t] = ((const uint4*)(feats + (size_t)i * N))[t];
    __syncthreads();
    float di = diag[i];
    for (int jj = 0; jj < 16; ++jj) {
        int j = w * 16 + jj;
        const uint4* fj = (const uint4*)(feats + (size_t)j * N);
        const uint4* fi = (const uint4*)s_fi;
        int s = 0;
#pragma unroll
        for (int k = 0; k < 4; ++k) {
            uint4 vb = fj[lane + k * 64];
            uint4 va = fi[lane + k * 64];
            s += (int)(va.x * vb.x) + (int)(va.y * vb.y)
               + (int)(va.z * vb.z) + (int)(va.w * vb.w);
        }
#pragma unroll
        for (int off = 32; off > 0; off >>= 1) s += __shfl_down(s, off);
        if (lane == 0) out[i * B + j] = (float)s / sqrtf(di * diag[j]);
    }
}

extern "C" void kernel_launch(void* const* d_in, const int* in_sizes, int n_in,
                              void* d_out, int out_size, void* d_ws, size_t ws_size,
                              hipStream_t stream) {
    const int*   esrc = (const int*)d_in[0];
    const int*   edst = (const int*)d_in[1];
    const int*   lab0 = (const int*)d_in[2];
    const float* hw   = (const float*)d_in[3];

    char* ws = (char*)d_ws;
    unsigned int* feats = (unsigned int*)(ws + FEATS_OFF);
    float*        diag  = (float*)(ws + DIAG_OFF);

    wl_mega_k<<<B, 1024, 0, stream>>>(esrc, edst, lab0, hw, feats, diag);
    gram_k<<<B, 256, 0, stream>>>(feats, diag, (float*)d_out);
}